// Round 2
// baseline (579.220 us; speedup 1.0000x reference)
//
#include <hip/hip_runtime.h>
#include <math.h>

#define N_NODES 32768
#define E_EDGES 524288
#define HIDDEN  256
#define NPG     512
#define NGRAPH  64
#define NHEAD   8
#define CDIM    32

typedef unsigned short bf16;
typedef __attribute__((ext_vector_type(8))) short short8;
typedef __attribute__((ext_vector_type(4))) float f4;

#define AS1 __attribute__((address_space(1)))
#define AS3 __attribute__((address_space(3)))

__device__ __forceinline__ void cp16(const bf16* g, bf16* l) {
    __builtin_amdgcn_global_load_lds((AS1 const unsigned int*)(const void*)g,
                                     (AS3 unsigned int*)(void*)l, 16, 0, 0);
}

// ---------------- bf16 helpers ----------------
__device__ inline float bf2f(unsigned short u) {
    union { unsigned int i; float f; } v; v.i = ((unsigned int)u) << 16; return v.f;
}
__device__ inline unsigned short f2bf(float f) {
    union { float f; unsigned int i; } v; v.f = f;
    unsigned int x = v.i;
    return (unsigned short)((x + 0x7FFFu + ((x >> 16) & 1u)) >> 16);
}
__device__ inline unsigned short f2bf_trunc(float f) {
    return (unsigned short)(__float_as_uint(f) >> 16);
}
__device__ inline float4 load4(const float* p) { return *(const float4*)p; }
__device__ inline float4 load4(const bf16* p) {
    ushort4 u = *(const ushort4*)p;
    return make_float4(bf2f(u.x), bf2f(u.y), bf2f(u.z), bf2f(u.w));
}
__device__ inline void store4(float* p, float4 v) { *(float4*)p = v; }
__device__ inline void store4(bf16* p, float4 v) {
    ushort4 u; u.x = f2bf(v.x); u.y = f2bf(v.y); u.z = f2bf(v.z); u.w = f2bf(v.w);
    *(ushort4*)p = u;
}

// fast exact-erf GELU: Abramowitz-Stegun 7.1.26, |err| <= 1.5e-7
__device__ __forceinline__ float gelu_fast(float x) {
    float z = fabsf(x) * 0.70710678118654752f;
    float t = 1.0f / (1.0f + 0.3275911f * z);
    float poly = t * (0.254829592f + t * (-0.284496736f + t * (1.421413741f
               + t * (-1.453152027f + t * 1.061405429f))));
    float erfv = 1.0f - poly * __expf(-z * z);
    erfv = copysignf(erfv, x);
    return 0.5f * x * (1.0f + erfv);
}

// ---------------- small utility kernels ----------------

__global__ void zero_kernel(float* deg, float* ea_sum, int* fill) {
    int i = blockIdx.x * blockDim.x + threadIdx.x;
    if (i < 2 * N_NODES) ea_sum[i] = 0.0f;
    if (i < N_NODES) { deg[i] = 0.0f; fill[i] = 0; }
}

__global__ void deg_kernel(const int* __restrict__ ei, const float* __restrict__ edge_attr,
                           float* deg, float* ea_sum) {
    int e = blockIdx.x * blockDim.x + threadIdx.x;
    if (e >= E_EDGES) return;
    int d = ei[E_EDGES + e];
    atomicAdd(&deg[d], 1.0f);
    atomicAdd(&ea_sum[2 * d + 0], edge_attr[2 * e + 0]);
    atomicAdd(&ea_sum[2 * d + 1], edge_attr[2 * e + 1]);
}

__global__ __launch_bounds__(1024) void scan_kernel(const float* __restrict__ deg, int* row_ptr) {
    __shared__ int part[1024];
    int t = threadIdx.x;
    int base = t * 32;
    int loc[32];
    int s = 0;
    #pragma unroll
    for (int j = 0; j < 32; j++) {
        loc[j] = s;
        s += (int)deg[base + j] + 1;
    }
    int mysum = s;
    part[t] = s;
    __syncthreads();
    for (int off = 1; off < 1024; off <<= 1) {
        int v = 0;
        if (t >= off) v = part[t - off];
        __syncthreads();
        part[t] += v;
        __syncthreads();
    }
    int offset = part[t] - mysum;
    #pragma unroll
    for (int j = 0; j < 32; j++) row_ptr[base + j] = offset + loc[j];
    if (t == 1023) row_ptr[N_NODES] = part[1023];
}

// CSR fill with PACKED 16B edge records: {src, ea0, ea1, 0}; self-loop mean inline
__global__ void fill_kernel(const int* __restrict__ ei, const float* __restrict__ edge_attr,
                            const float* __restrict__ ea_sum, const float* __restrict__ deg,
                            const int* __restrict__ row_ptr, int* fill, int4* __restrict__ erec) {
    int tid = blockIdx.x * blockDim.x + threadIdx.x;
    if (tid >= E_EDGES + N_NODES) return;
    int d, src; float a0, a1;
    if (tid < E_EDGES) {
        d = ei[E_EDGES + tid];
        src = ei[tid];
        a0 = edge_attr[2 * tid + 0];
        a1 = edge_attr[2 * tid + 1];
    } else {
        d = tid - E_EDGES;
        src = d;
        float dm = fmaxf(deg[d], 1.0f);
        a0 = ea_sum[2 * d + 0] / dm;
        a1 = ea_sum[2 * d + 1] / dm;
    }
    int pos = row_ptr[d] + atomicAdd(&fill[d], 1);
    int4 r;
    r.x = src;
    r.y = __float_as_int(a0);
    r.z = __float_as_int(a1);
    r.w = 0;
    erec[pos] = r;
}

// ---------------- all conversions in one launch ----------------
// wcat rows: 0..767 in_proj (q rows prescaled by SCALE*log2e), 768..1023 W_l^T, 1024..1279 W_r^T
#define QSCALE 0.25506882685716462f
__global__ void convall(const float* __restrict__ x,
                        const float* __restrict__ W_l, const float* __restrict__ W_r,
                        const float* __restrict__ W1, const float* __restrict__ W2,
                        const float* __restrict__ in_proj_w, const float* __restrict__ out_proj_w,
                        const float* __restrict__ b_l, const float* __restrict__ b_r,
                        const float* __restrict__ in_proj_b,
                        bf16* xb, bf16* wcat, bf16* w1b, bf16* w2b,
                        bf16* wopb, float* bcat)
{
    int b = blockIdx.x, t = threadIdx.x;
    if (b < 8192) {                      // x copy (float4)
        int i = b * 256 + t;
        store4(&xb[i * 4], *(const float4*)&x[i * 4]);
    } else if (b < 8960) {               // in_proj_w [768][256] copy; q rows scaled
        int i = (b - 8192) * 256 + t;
        float v = in_proj_w[i];
        if (i < 65536) v *= QSCALE;
        wcat[i] = f2bf(v);
    } else if (b < 9216) {               // W_l^T -> wcat rows 768..1023
        int i = (b - 8960) * 256 + t; int k = i >> 8, n = i & 255;
        wcat[(768 + n) * 256 + k] = f2bf(W_l[i]);
    } else if (b < 9472) {               // W_r^T -> wcat rows 1024..1279
        int i = (b - 9216) * 256 + t; int k = i >> 8, n = i & 255;
        wcat[(1024 + n) * 256 + k] = f2bf(W_r[i]);
    } else if (b < 10496) {              // W1 [256][1024] -> w1b[n*256+k]
        int i = (b - 9472) * 256 + t; int k = i >> 10, n = i & 1023;
        w1b[n * 256 + k] = f2bf(W1[i]);
    } else if (b < 11520) {              // W2 [1024][256] -> w2b[n*1024+k]
        int i = (b - 10496) * 256 + t; int k = i >> 8, n = i & 255;
        w2b[n * 1024 + k] = f2bf(W2[i]);
    } else if (b < 11584) {              // out_proj_w straight
        int i = (b - 11520) * 256 + t;
        store4(&wopb[i * 4], *(const float4*)&out_proj_w[i * 4]);
    } else {                             // bcat: scaled in_proj_b | b_l | b_r
        #pragma unroll
        for (int j = 0; j < 5; j++) {
            int idx = j * 256 + t;
            float v;
            if (idx < 768) { v = in_proj_b[idx]; if (idx < 256) v *= QSCALE; }
            else if (idx < 1024) v = b_l[idx - 768];
            else v = b_r[idx - 1024];
            bcat[idx] = v;
        }
    }
}

// ---------------- MFMA bf16 GEMM (m97-style staging + XCD-locality swizzle) --
// EPI: 0 bias, 1 bias+gelu, 4 bias+residual(res bf16)->fp32 (float*)C,
//      5 merged 5-slab routing: slabs 0-2 -> qkv[gm*768+gn], 3 -> res(xl), 4 -> d2(xr)
template <int EPI>
__global__ __launch_bounds__(256) void mfma_gemm(
    const bf16* __restrict__ A, const bf16* __restrict__ Wb,
    const float* __restrict__ bias, const bf16* __restrict__ res,
    bf16* __restrict__ C, int M, int N, int K, bf16* __restrict__ d2)
{
    __shared__ bf16 lds[2 * 128 * 64];
    bf16* As = lds;
    bf16* Bs = lds + 128 * 64;
    int tid = threadIdx.x;
    int wave = tid >> 6, lane = tid & 63;
    int quad = lane >> 4, l16 = lane & 15;
    // XCD-bijective swizzle: blocks sharing an A-tile (same by) land on ONE XCD
    int nbx = gridDim.x;
    int lid = blockIdx.y * nbx + blockIdx.x;
    int chunk = (nbx * gridDim.y) >> 3;
    int nlid = (lid & 7) * chunk + (lid >> 3);
    int bx = nlid % nbx;
    int by = nlid / nbx;
    int n0 = bx * 128, m0 = by * 128;
    int wm = (wave & 1) * 64, wn = (wave >> 1) * 64;

    f4 acc[4][4] = {};
    int srow = tid >> 3;
    int scol = (tid & 7) * 8;

    for (int k0 = 0; k0 < K; k0 += 64) {
        #pragma unroll
        for (int i = 0; i < 4; i++) {
            int row = i * 32 + srow;
            cp16(&A[(size_t)(m0 + row) * K + k0 + scol], &As[row * 64 + scol]);
            cp16(&Wb[(size_t)(n0 + row) * K + k0 + scol], &Bs[row * 64 + scol]);
        }
        __syncthreads();
        #pragma unroll
        for (int ks = 0; ks < 2; ks++) {
            short8 af[4], bfr[4];
            #pragma unroll
            for (int mt = 0; mt < 4; mt++)
                af[mt] = *(const short8*)&As[(wm + mt * 16 + l16) * 64 + ks * 32 + quad * 8];
            #pragma unroll
            for (int nt = 0; nt < 4; nt++)
                bfr[nt] = *(const short8*)&Bs[(wn + nt * 16 + l16) * 64 + ks * 32 + quad * 8];
            #pragma unroll
            for (int mt = 0; mt < 4; mt++)
                #pragma unroll
                for (int nt = 0; nt < 4; nt++)
                    acc[mt][nt] = __builtin_amdgcn_mfma_f32_16x16x32_bf16(
                        af[mt], bfr[nt], acc[mt][nt], 0, 0, 0);
        }
        __syncthreads();
    }

    float* epi = (float*)lds + wave * 16 * 68;
    int row = lane >> 2;
    int cb = (lane & 3) * 16;
    int gn = n0 + wn + cb;
    float bb[16];
    *(float4*)&bb[0]  = *(const float4*)&bias[gn + 0];
    *(float4*)&bb[4]  = *(const float4*)&bias[gn + 4];
    *(float4*)&bb[8]  = *(const float4*)&bias[gn + 8];
    *(float4*)&bb[12] = *(const float4*)&bias[gn + 12];

    for (int mt = 0; mt < 4; mt++) {
        #pragma unroll
        for (int nt = 0; nt < 4; nt++)
            #pragma unroll
            for (int r = 0; r < 4; r++)
                epi[(quad * 4 + r) * 68 + nt * 16 + l16] = acc[mt][nt][r];
        float vv[16];
        *(float4*)&vv[0]  = *(float4*)&epi[row * 68 + cb + 0];
        *(float4*)&vv[4]  = *(float4*)&epi[row * 68 + cb + 4];
        *(float4*)&vv[8]  = *(float4*)&epi[row * 68 + cb + 8];
        *(float4*)&vv[12] = *(float4*)&epi[row * 68 + cb + 12];
        int gm = m0 + wm + mt * 16 + row;
        #pragma unroll
        for (int j = 0; j < 16; j++) vv[j] += bb[j];
        if (EPI == 1) {
            #pragma unroll
            for (int j = 0; j < 16; j++)
                vv[j] = gelu_fast(vv[j]);
        } else if (EPI == 4) {
            ushort rr[16];
            const bf16* rp = &res[(size_t)gm * N + gn];
            *(int4*)&rr[0] = *(const int4*)&rp[0];
            *(int4*)&rr[8] = *(const int4*)&rp[8];
            #pragma unroll
            for (int j = 0; j < 16; j++) vv[j] += bf2f(rr[j]);
            float* cf = (float*)C + (size_t)gm * N + gn;
            *(float4*)&cf[0]  = *(float4*)&vv[0];
            *(float4*)&cf[4]  = *(float4*)&vv[4];
            *(float4*)&cf[8]  = *(float4*)&vv[8];
            *(float4*)&cf[12] = *(float4*)&vv[12];
            continue;
        }
        ushort o16[16];
        #pragma unroll
        for (int j = 0; j < 16; j++) o16[j] = f2bf(vv[j]);
        bf16* cp;
        if (EPI == 5) {
            if (gn < 768) {
                cp = &C[(size_t)gm * 768 + gn];           // interleaved qkv
            } else if (gn < 1024) {
                cp = &((bf16*)res)[(size_t)gm * 256 + (gn - 768)];   // xl
            } else {
                cp = &d2[(size_t)gm * 256 + (gn - 1024)];            // xr
            }
        } else {
            cp = &C[(size_t)gm * N + gn];
        }
        *(int4*)&cp[0] = *(int4*)&o16[0];
        *(int4*)&cp[8] = *(int4*)&o16[8];
    }
}

// ---------------- fused FFN: gelu(combined@W1+b1)@W2+b2 + residual + LN3 ----
// One 64-row slab per block.  16 chunks of 64 h1-cols.  LDS = 72 KB ->
// 2 blocks/CU (the 113KB/1-block version was 1 wave/SIMD: zero latency
// hiding, MfmaUtil 11%).  fp32 LN3 buffer aliases Asl+WB (dead by then).
// All tiles XOR-swizzled (byte ^= (row&7)<<4) on BOTH sides (m201 rule).
__global__ __launch_bounds__(256) void ffn_fused(
    const bf16* __restrict__ combined,
    const bf16* __restrict__ w1b, const bf16* __restrict__ w2b,
    const float* __restrict__ b1, const float* __restrict__ b2,
    const float* __restrict__ g3, const float* __restrict__ be3,
    float* __restrict__ out)
{
    __shared__ __attribute__((aligned(16))) char smem[73728];
    char* Asl_c = smem;                // 32 KB combined slab (swz512)
    char* WB_c  = smem + 32768;        // 32 KB W1chunk(swz512) / W2chunk(swz128), time-shared
    char* H1_c  = smem + 65536;        //  8 KB h1 chunk [64][64] (swz128)

    int tid = threadIdx.x;
    int wave = tid >> 6, lane = tid & 63;
    int quad = lane >> 4, l16 = lane & 15;
    int m0 = blockIdx.x * 64;
    int wn1 = wave * 16;               // gemm1 n-strip within chunk (16 h1-cols/wave)
    int wn2 = wave * 64;               // gemm2 out-col strip

    // stage combined slab: linear dest o, source from logical L = o^swz
    #pragma unroll
    for (int rr = 0; rr < 8; rr++) {
        int o = rr * 4096 + tid * 16;
        int L = o ^ (((o >> 9) & 7) << 4);
        int row = L >> 9, colb = L & 511;
        cp16((const bf16*)((const char*)combined + (size_t)(m0 + row) * 512 + colb),
             (bf16*)(Asl_c + o));
    }

    f4 oacc[4][4] = {};

    for (int j = 0; j < 16; j++) {
        if (j) __syncthreads();                       // WB/H1 free of prev gemm2 reads
        // stage W1 chunk [64 n][256 k] (rows j*64.. of w1b)
        #pragma unroll
        for (int rr = 0; rr < 8; rr++) {
            int o = rr * 4096 + tid * 16;
            int L = o ^ (((o >> 9) & 7) << 4);
            int row = L >> 9, colb = L & 511;
            cp16((const bf16*)((const char*)w1b + (size_t)(j * 64 + row) * 512 + colb),
                 (bf16*)(WB_c + o));
        }
        __syncthreads();                              // A + W1 visible

        // gemm1: 64x64 over K=256
        f4 acc1[4] = {};
        #pragma unroll
        for (int ks = 0; ks < 8; ks++) {
            short8 af[4], bf1;
            #pragma unroll
            for (int mt = 0; mt < 4; mt++) {
                int r_ = mt * 16 + l16;
                af[mt] = *(const short8*)(Asl_c +
                    ((r_ * 512 + ks * 64 + quad * 16) ^ ((r_ & 7) << 4)));
            }
            {
                int r_ = wn1 + l16;
                bf1 = *(const short8*)(WB_c +
                    ((r_ * 512 + ks * 64 + quad * 16) ^ ((r_ & 7) << 4)));
            }
            #pragma unroll
            for (int mt = 0; mt < 4; mt++)
                acc1[mt] = __builtin_amdgcn_mfma_f32_16x16x32_bf16(
                    af[mt], bf1, acc1[mt], 0, 0, 0);
        }
        float b1v = b1[j * 64 + wn1 + l16];
        __syncthreads();                              // all WB(W1) reads done
        // gelu -> H1 chunk (swz128)
        #pragma unroll
        for (int mt = 0; mt < 4; mt++)
            #pragma unroll
            for (int r = 0; r < 4; r++) {
                float v = gelu_fast(acc1[mt][r] + b1v);
                int row = mt * 16 + quad * 4 + r;
                int cb2 = (row * 128 + (wn1 + l16) * 2) ^ ((row & 7) << 4);
                *(bf16*)(H1_c + cb2) = f2bf(v);
            }
        // stage W2 chunk [256 n][64 k'] (cols j*64.. of w2b rows)
        #pragma unroll
        for (int rr = 0; rr < 8; rr++) {
            int o = rr * 4096 + tid * 16;
            int L = o ^ (((o >> 7) & 7) << 4);
            int row = L >> 7, colb = L & 127;
            cp16((const bf16*)((const char*)w2b + (size_t)row * 2048 + j * 128 + colb),
                 (bf16*)(WB_c + o));
        }
        __syncthreads();                              // H1 + W2 visible
        // gemm2 partial: oacc += h1chunk @ W2chunk (K'=64)
        #pragma unroll
        for (int ks = 0; ks < 2; ks++) {
            short8 af2[4], bf2v[4];
            #pragma unroll
            for (int mt = 0; mt < 4; mt++) {
                int row = mt * 16 + l16;
                af2[mt] = *(const short8*)(H1_c +
                    ((row * 128 + ks * 64 + quad * 16) ^ ((row & 7) << 4)));
            }
            #pragma unroll
            for (int nt = 0; nt < 4; nt++) {
                int r_ = wn2 + nt * 16 + l16;
                bf2v[nt] = *(const short8*)(WB_c +
                    ((r_ * 128 + ks * 64 + quad * 16) ^ ((r_ & 7) << 4)));
            }
            #pragma unroll
            for (int mt = 0; mt < 4; mt++)
                #pragma unroll
                for (int nt = 0; nt < 4; nt++)
                    oacc[mt][nt] = __builtin_amdgcn_mfma_f32_16x16x32_bf16(
                        af2[mt], bf2v[nt], oacc[mt][nt], 0, 0, 0);
        }
    }

    // epilogue: bias + residual(from Asl, swizzled) folded into regs
    #pragma unroll
    for (int nt = 0; nt < 4; nt++) {
        float b2v = b2[wn2 + nt * 16 + l16];
        #pragma unroll
        for (int mt = 0; mt < 4; mt++)
            #pragma unroll
            for (int r = 0; r < 4; r++) {
                int rl = mt * 16 + quad * 4 + r;
                int gn = wn2 + nt * 16 + l16;
                int o = (rl * 512 + gn * 2) ^ ((rl & 7) << 4);
                oacc[mt][nt][r] += b2v + bf2f(*(const bf16*)(Asl_c + o));
            }
    }
    __syncthreads();                                  // last gemm2/Asl reads done
    float* pre = (float*)smem;                        // 64x256 fp32 = 64 KB (aliases Asl+WB)
    #pragma unroll
    for (int mt = 0; mt < 4; mt++)
        #pragma unroll
        for (int nt = 0; nt < 4; nt++)
            #pragma unroll
            for (int r = 0; r < 4; r++)
                pre[(mt * 16 + quad * 4 + r) * 256 + wn2 + nt * 16 + l16] = oacc[mt][nt][r];
    __syncthreads();
    // LN3: each wave owns 16 full rows
    float4 gv  = *(const float4*)&g3[lane * 4];
    float4 bev = *(const float4*)&be3[lane * 4];
    for (int rr = 0; rr < 16; rr++) {
        int row = wave * 16 + rr;
        float4 v = *(const float4*)&pre[row * 256 + lane * 4];
        float s = v.x + v.y + v.z + v.w;
        #pragma unroll
        for (int m = 1; m < 64; m <<= 1) s += __shfl_xor(s, m);
        float mean = s * (1.0f / 256.0f);
        float d0 = v.x - mean, d1 = v.y - mean, d2 = v.z - mean, d3 = v.w - mean;
        float sq = d0 * d0 + d1 * d1 + d2 * d2 + d3 * d3;
        #pragma unroll
        for (int m = 1; m < 64; m <<= 1) sq += __shfl_xor(sq, m);
        float rstd = rsqrtf(sq * (1.0f / 256.0f) + 1e-5f);
        float4 o;
        o.x = d0 * rstd * gv.x + bev.x;
        o.y = d1 * rstd * gv.y + bev.y;
        o.z = d2 * rstd * gv.z + bev.z;
        o.w = d3 * rstd * gv.w + bev.w;
        *(float4*)&out[(size_t)(m0 + row) * 256 + lane * 4] = o;
    }
}

// ---------------- MFMA flash attention (q prescaled; exp2; trunc pack) ----
__global__ __launch_bounds__(256) void attn_mfma(
    const bf16* __restrict__ qkv, bf16* __restrict__ attnout)
{
    __shared__ bf16 Ks[128 * 40];
    __shared__ bf16 Vt[32 * 136];
    __shared__ bf16 Pb[4 * 64 * 40];

    int b = blockIdx.x;
    int g = b >> 4, h = (b >> 1) & 7, hlf = b & 1;
    int tid = threadIdx.x;
    int wave = tid >> 6, lane = tid & 63;
    int quad = lane >> 4, l16 = lane & 15;
    int qbase = hlf * 256 + wave * 64;
    bf16* Pw = &Pb[wave * 64 * 40];

    short8 qf[4];
    #pragma unroll
    for (int mt = 0; mt < 4; mt++) {
        size_t node = (size_t)(g * NPG + qbase + mt * 16 + l16);
        qf[mt] = *(const short8*)&qkv[node * 768 + h * CDIM + quad * 8];
    }

    f4 oacc[4][2] = {};
    float lacc[4][4] = {};

    for (int c = 0; c < 4; c++) {
        int kk0 = c * 128;
        __syncthreads();
        #pragma unroll
        for (int i = 0; i < 2; i++) {
            int idx = i * 256 + tid;
            int key = idx >> 2, kc = (idx & 3) * 8;
            *(int4*)&Ks[key * 40 + kc] =
                *(const int4*)&qkv[(size_t)(g * NPG + kk0 + key) * 768 + 256 + h * CDIM + kc];
        }
        {
            int key = tid >> 1, dblk = (tid & 1) * 16;
            ushort tmp[16];
            const bf16* vp = &qkv[(size_t)(g * NPG + kk0 + key) * 768 + 512 + h * CDIM + dblk];
            *(int4*)&tmp[0] = *(const int4*)&vp[0];
            *(int4*)&tmp[8] = *(const int4*)&vp[8];
            #pragma unroll
            for (int j = 0; j < 16; j++) Vt[(dblk + j) * 136 + key] = tmp[j];
        }
        __syncthreads();

        for (int sub = 0; sub < 4; sub++) {
            int ks0 = sub * 32;
            short8 kf[2];
            #pragma unroll
            for (int nt = 0; nt < 2; nt++)
                kf[nt] = *(const short8*)&Ks[(ks0 + nt * 16 + l16) * 40 + quad * 8];
            #pragma unroll
            for (int mt = 0; mt < 4; mt++) {
                #pragma unroll
                for (int nt = 0; nt < 2; nt++) {
                    f4 z = {0.f, 0.f, 0.f, 0.f};
                    f4 s = __builtin_amdgcn_mfma_f32_16x16x32_bf16(qf[mt], kf[nt], z, 0, 0, 0);
                    #pragma unroll
                    for (int r = 0; r < 4; r++) {
                        float p = exp2f(s[r]);
                        lacc[mt][r] += p;
                        Pw[(mt * 16 + quad * 4 + r) * 40 + nt * 16 + l16] = f2bf_trunc(p);
                    }
                }
            }
            short8 vf[2];
            #pragma unroll
            for (int dt = 0; dt < 2; dt++)
                vf[dt] = *(const short8*)&Vt[(dt * 16 + l16) * 136 + ks0 + quad * 8];
            #pragma unroll
            for (int mt = 0; mt < 4; mt++) {
                short8 pf = *(const short8*)&Pw[(mt * 16 + l16) * 40 + quad * 8];
                #pragma unroll
                for (int dt = 0; dt < 2; dt++)
                    oacc[mt][dt] = __builtin_amdgcn_mfma_f32_16x16x32_bf16(
                        pf, vf[dt], oacc[mt][dt], 0, 0, 0);
            }
        }
    }

    #pragma unroll
    for (int mt = 0; mt < 4; mt++)
        #pragma unroll
        for (int r = 0; r < 4; r++) {
            float l = lacc[mt][r];
            l += __shfl_xor(l, 1);
            l += __shfl_xor(l, 2);
            l += __shfl_xor(l, 4);
            l += __shfl_xor(l, 8);
            lacc[mt][r] = l;
        }

    #pragma unroll
    for (int mt = 0; mt < 4; mt++) {
        #pragma unroll
        for (int dt = 0; dt < 2; dt++) {
            #pragma unroll
            for (int r = 0; r < 4; r++) {
                float v = oacc[mt][dt][r] / lacc[mt][r];
                size_t node = (size_t)(g * NPG + qbase + mt * 16 + quad * 4 + r);
                attnout[node * HIDDEN + h * CDIM + dt * 16 + l16] = f2bf(v);
            }
        }
    }
}

// ---------------- GATv2: 2 waves/node + depth-2 pipeline (r8-proven) ----
__device__ __forceinline__ void fetchrec(
    int i, int re, int node, const int4* __restrict__ erec,
    int& s, float& a0, float& a1)
{
    if (i < re) {
        int4 r = erec[i];
        s = r.x; a0 = __int_as_float(r.y); a1 = __int_as_float(r.z);
    } else {
        s = node; a0 = 0.f; a1 = 0.f;
    }
}

__global__ __launch_bounds__(256) void gat_kernel(
    const bf16* __restrict__ xl, const bf16* __restrict__ xr,
    const int* __restrict__ row_ptr, const int4* __restrict__ erec,
    const float* __restrict__ W_e, const float* __restrict__ att,
    const float* __restrict__ bias_gat,
    const float* __restrict__ g1, const float* __restrict__ be1,
    bf16* __restrict__ out)
{
    __shared__ float pacc[2][260];
    __shared__ float plsum[2][64];
    int wave = threadIdx.x >> 6;
    int lane = threadIdx.x & 63;
    int nloc = wave >> 1, half = wave & 1;
    int node = blockIdx.x * 2 + nloc;
    int cb = lane * 4;

    float4 xr4 = load4(&xr[(size_t)node * 256 + cb]);
    float4 we0 = *(const float4*)&W_e[cb];
    float4 we1 = *(const float4*)&W_e[HIDDEN + cb];
    float4 at4 = *(const float4*)&att[cb];

    int rs = row_ptr[node], re = row_ptr[node + 1];

    float lsum = 0.f;
    float acc0 = 0.f, acc1 = 0.f, acc2 = 0.f, acc3 = 0.f;

    int i0 = rs + half;
    int s0, s1; float a00, a01, a10, a11;
    fetchrec(i0,     re, node, erec, s0, a00, a01);
    fetchrec(i0 + 2, re, node, erec, s1, a10, a11);
    ushort4 xu0 = *(const ushort4*)&xl[(size_t)s0 * 256 + cb];

    for (int i = i0; i < re; i += 2) {
        int s2; float a20, a21;
        fetchrec(i + 4, re, node, erec, s2, a20, a21);
        ushort4 xu1 = *(const ushort4*)&xl[(size_t)s1 * 256 + cb];

        float4 xl4 = make_float4(bf2f(xu0.x), bf2f(xu0.y), bf2f(xu0.z), bf2f(xu0.w));
        float t, p = 0.f;
        t = xl4.x + xr4.x + a00 * we0.x + a01 * we1.x; t = (t > 0.f) ? t : 0.2f * t; p += t * at4.x;
        t = xl4.y + xr4.y + a00 * we0.y + a01 * we1.y; t = (t > 0.f) ? t : 0.2f * t; p += t * at4.y;
        t = xl4.z + xr4.z + a00 * we0.z + a01 * we1.z; t = (t > 0.f) ? t : 0.2f * t; p += t * at4.z;
        t = xl4.w + xr4.w + a00 * we0.w + a01 * we1.w; t = (t > 0.f) ? t : 0.2f * t; p += t * at4.w;
        p += __shfl_xor(p, 1);
        p += __shfl_xor(p, 2);
        p += __shfl_xor(p, 4);
        float w = __expf(p);
        lsum += w;
        acc0 += w * xl4.x; acc1 += w * xl4.y; acc2 += w * xl4.z; acc3 += w * xl4.w;

        s0 = s1; a00 = a10; a01 = a11; xu0 = xu1;
        s1 = s2; a10 = a20; a11 = a21;
    }

    if (half) {
        plsum[nloc][lane] = lsum;
        pacc[nloc][cb + 0] = acc0; pacc[nloc][cb + 1] = acc1;
        pacc[nloc][cb + 2] = acc2; pacc[nloc][cb + 3] = acc3;
    }
    __syncthreads();
    if (!half) {
        lsum += plsum[nloc][lane];
        acc0 += pacc[nloc][cb + 0]; acc1 += pacc[nloc][cb + 1];
        acc2 += pacc[nloc][cb + 2]; acc3 += pacc[nloc][cb + 3];

        float inv = 1.0f / lsum;
        float v0 = acc0 * inv + bias_gat[cb + 0];
        float v1 = acc1 * inv + bias_gat[cb + 1];
        float v2 = acc2 * inv + bias_gat[cb + 2];
        float v3 = acc3 * inv + bias_gat[cb + 3];

        float s = v0 + v1 + v2 + v3;
        #pragma unroll
        for (int m = 1; m < 64; m <<= 1) s += __shfl_xor(s, m);
        float mean = s * (1.0f / 256.0f);
        float d0 = v0 - mean, d1 = v1 - mean, d2 = v2 - mean, d3 = v3 - mean;
        float sq = d0 * d0 + d1 * d1 + d2 * d2 + d3 * d3;
        #pragma unroll
        for (int m = 1; m < 64; m <<= 1) sq += __shfl_xor(sq, m);
        float rstd = rsqrtf(sq * (1.0f / 256.0f) + 1e-5f);
        float4 o;
        o.x = d0 * rstd * g1[cb + 0] + be1[cb + 0];
        o.y = d1 * rstd * g1[cb + 1] + be1[cb + 1];
        o.z = d2 * rstd * g1[cb + 2] + be1[cb + 2];
        o.w = d3 * rstd * g1[cb + 3] + be1[cb + 3];
        store4(&out[(size_t)node * HIDDEN + cb], o);
    }
}

// ---------------- LN2(gout) + gated combine ----------------
__global__ __launch_bounds__(256) void combine_kernel(
    const bf16* __restrict__ gout, const bf16* __restrict__ localout,
    const float* __restrict__ alpha_p,
    const float* __restrict__ g2, const float* __restrict__ be2,
    bf16* __restrict__ combined)
{
    int wave = threadIdx.x >> 6;
    int lane = threadIdx.x & 63;
    int node = blockIdx.x * 4 + wave;
    int cb = lane * 4;
    float4 gv = load4(&gout[(size_t)node * HIDDEN + cb]);
    float s = gv.x + gv.y + gv.z + gv.w;
    #pragma unroll
    for (int m = 1; m < 64; m <<= 1) s += __shfl_xor(s, m);
    float mean = s * (1.0f / 256.0f);
    float d0 = gv.x - mean, d1 = gv.y - mean, d2 = gv.z - mean, d3 = gv.w - mean;
    float sq = d0 * d0 + d1 * d1 + d2 * d2 + d3 * d3;
    #pragma unroll
    for (int m = 1; m < 64; m <<= 1) sq += __shfl_xor(sq, m);
    float rstd = rsqrtf(sq * (1.0f / 256.0f) + 1e-5f);
    float n0 = d0 * rstd * g2[cb + 0] + be2[cb + 0];
    float n1 = d1 * rstd * g2[cb + 1] + be2[cb + 1];
    float n2 = d2 * rstd * g2[cb + 2] + be2[cb + 2];
    float n3 = d3 * rstd * g2[cb + 3] + be2[cb + 3];
    float a = 1.0f / (1.0f + __expf(-alpha_p[0]));
    float4 lv = load4(&localout[(size_t)node * HIDDEN + cb]);
    float4 o;
    o.x = a * lv.x + (1.0f - a) * n0;
    o.y = a * lv.y + (1.0f - a) * n1;
    o.z = a * lv.z + (1.0f - a) * n2;
    o.w = a * lv.w + (1.0f - a) * n3;
    store4(&combined[(size_t)node * HIDDEN + cb], o);
}

// ---------------- launch ----------------
extern "C" void kernel_launch(void* const* d_in, const int* in_sizes, int n_in,
                              void* d_out, int out_size, void* d_ws, size_t ws_size,
                              hipStream_t stream) {
    const float* x          = (const float*)d_in[0];
    const float* edge_attr  = (const float*)d_in[1];
    const float* W_l        = (const float*)d_in[2];
    const float* b_l        = (const float*)d_in[3];
    const float* W_r        = (const float*)d_in[4];
    const float* b_r        = (const float*)d_in[5];
    const float* W_e        = (const float*)d_in[6];
    const float* att        = (const float*)d_in[7];
    const float* bias_gat   = (const float*)d_in[8];
    const float* in_proj_w  = (const float*)d_in[9];
    const float* in_proj_b  = (const float*)d_in[10];
    const float* out_proj_w = (const float*)d_in[11];
    const float* out_proj_b = (const float*)d_in[12];
    const float* alpha_p    = (const float*)d_in[13];
    const float* W1         = (const float*)d_in[14];
    const float* b1         = (const float*)d_in[15];
    const float* W2         = (const float*)d_in[16];
    const float* b2         = (const float*)d_in[17];
    const float* g1  = (const float*)d_in[18];
    const float* be1 = (const float*)d_in[19];
    const float* g2  = (const float*)d_in[20];
    const float* be2 = (const float*)d_in[21];
    const float* g3  = (const float*)d_in[22];
    const float* be3 = (const float*)d_in[23];
    const int* edge_index = (const int*)d_in[24];

    char* base = (char*)d_ws;
    const size_t MB = 1024 * 1024;
    const size_t KB = 1024;
    // graph prep [0, 3 MiB)
    float* deg     = (float*)(base + 0);
    float* ea_sum  = (float*)(base + 131072);
    int*   fill    = (int*)  (base + 393216);
    int*   row_ptr = (int*)  (base + 524288);
    // bf16 weights [3 MiB, ~5 MiB)
    bf16* wcat = (bf16*)(base + 3 * MB);              // 1280x256 (640 KB)
    bf16* w1b  = (bf16*)(base + 3 * MB + 704 * KB);   // 1024x256 (512 KB)
    bf16* w2b  = (bf16*)(base + 3 * MB + 1216 * KB);  // 256x1024 (512 KB)
    bf16* wopb = (bf16*)(base + 3 * MB + 1728 * KB);  // 256x256  (128 KB)
    float* bcat = (float*)(base + 5 * MB);            // 1280 floats
    // big bf16 buffers (aliased)
    bf16* xb       = (bf16*)(base + 8 * MB);    // [8,24)
    bf16* qkv      = (bf16*)(base + 24 * MB);   // [24,72)  alive: merged GEMM .. attn
    bf16* attnout  = (bf16*)(base + 8 * MB);    // [8,24)   (xb dead after merged GEMM)
    bf16* gout     = (bf16*)(base + 24 * MB);   // [24,40)  (qkv dead after attn)
    bf16* localout = (bf16*)(base + 40 * MB);   // [40,56)
    bf16* combined = (bf16*)(base + 56 * MB);   // [56,72)
    int4* erec     = (int4*)(base + 88 * MB);   // [88, 96.6)
    bf16* xl_      = (bf16*)(base + 72 * MB);   // [72,88)
    bf16* xr_      = (bf16*)(base + 104 * MB);  // [104,120)
    float* out = (float*)d_out;

    // ---- GAT graph prep ----
    zero_kernel<<<(2 * N_NODES + 255) / 256, 256, 0, stream>>>(deg, ea_sum, fill);
    deg_kernel<<<E_EDGES / 256, 256, 0, stream>>>(edge_index, edge_attr, deg, ea_sum);
    scan_kernel<<<1, 1024, 0, stream>>>(deg, row_ptr);
    fill_kernel<<<(E_EDGES + N_NODES + 255) / 256, 256, 0, stream>>>(
        edge_index, edge_attr, ea_sum, deg, row_ptr, fill, erec);

    // ---- conversions (single launch) ----
    convall<<<11585, 256, 0, stream>>>(x, W_l, W_r, W1, W2, in_proj_w, out_proj_w,
                                       b_l, b_r, in_proj_b,
                                       xb, wcat, w1b, w2b, wopb, bcat);

    // ---- merged qkv|xl|xr GEMM (one pass over xb) ----
    mfma_gemm<5><<<dim3(10, 256), 256, 0, stream>>>(
        xb, wcat, bcat, xl_, qkv, N_NODES, 1280, 256, xr_);

    // ---- attention, then gat (qkv frees buffers for downstream) ----
    attn_mfma<<<NGRAPH * NHEAD * 2, 256, 0, stream>>>(qkv, attnout);
    gat_kernel<<<N_NODES / 2, 256, 0, stream>>>(
        xl_, xr_, row_ptr, erec, W_e, att, bias_gat, g1, be1, localout);

    // ---- out_proj ----
    mfma_gemm<0><<<dim3(2, 256), 256, 0, stream>>>(
        attnout, wopb, out_proj_b, (const bf16*)nullptr, gout, N_NODES, 256, 256, (bf16*)nullptr);

    // ---- LN2 + gated combine ----
    combine_kernel<<<N_NODES / 4, 256, 0, stream>>>(
        gout, localout, alpha_p, g2, be2, combined);

    // ---- fused FFN1+gelu+FFN2+residual+LN3 -> fp32 out ----
    ffn_fused<<<N_NODES / 64, 256, 0, stream>>>(
        combined, w1b, w2b, b1, b2, g3, be3, out);
}

// Round 3
// 537.105 us; speedup vs baseline: 1.0784x; 1.0784x over previous
//
#include <hip/hip_runtime.h>
#include <math.h>

#define N_NODES 32768
#define E_EDGES 524288
#define HIDDEN  256
#define NPG     512
#define NGRAPH  64
#define NHEAD   8
#define CDIM    32

typedef unsigned short bf16;
typedef __attribute__((ext_vector_type(8))) short short8;
typedef __attribute__((ext_vector_type(4))) float f4;

#define AS1 __attribute__((address_space(1)))
#define AS3 __attribute__((address_space(3)))

__device__ __forceinline__ void cp16(const bf16* g, bf16* l) {
    __builtin_amdgcn_global_load_lds((AS1 const unsigned int*)(const void*)g,
                                     (AS3 unsigned int*)(void*)l, 16, 0, 0);
}

// ---------------- bf16 helpers ----------------
__device__ inline float bf2f(unsigned short u) {
    union { unsigned int i; float f; } v; v.i = ((unsigned int)u) << 16; return v.f;
}
__device__ inline unsigned short f2bf(float f) {
    union { float f; unsigned int i; } v; v.f = f;
    unsigned int x = v.i;
    return (unsigned short)((x + 0x7FFFu + ((x >> 16) & 1u)) >> 16);
}
__device__ inline unsigned short f2bf_trunc(float f) {
    return (unsigned short)(__float_as_uint(f) >> 16);
}
__device__ inline float4 load4(const float* p) { return *(const float4*)p; }
__device__ inline float4 load4(const bf16* p) {
    ushort4 u = *(const ushort4*)p;
    return make_float4(bf2f(u.x), bf2f(u.y), bf2f(u.z), bf2f(u.w));
}
__device__ inline void store4(float* p, float4 v) { *(float4*)p = v; }
__device__ inline void store4(bf16* p, float4 v) {
    ushort4 u; u.x = f2bf(v.x); u.y = f2bf(v.y); u.z = f2bf(v.z); u.w = f2bf(v.w);
    *(ushort4*)p = u;
}

// fast exact-erf GELU: Abramowitz-Stegun 7.1.26, |err| <= 1.5e-7
__device__ __forceinline__ float gelu_fast(float x) {
    float z = fabsf(x) * 0.70710678118654752f;
    float t = 1.0f / (1.0f + 0.3275911f * z);
    float poly = t * (0.254829592f + t * (-0.284496736f + t * (1.421413741f
               + t * (-1.453152027f + t * 1.061405429f))));
    float erfv = 1.0f - poly * __expf(-z * z);
    erfv = copysignf(erfv, x);
    return 0.5f * x * (1.0f + erfv);
}

// ---------------- small utility kernels ----------------

__global__ void zero_kernel(float* deg, float* ea_sum, int* fill) {
    int i = blockIdx.x * blockDim.x + threadIdx.x;
    if (i < 2 * N_NODES) ea_sum[i] = 0.0f;
    if (i < N_NODES) { deg[i] = 0.0f; fill[i] = 0; }
}

__global__ void deg_kernel(const int* __restrict__ ei, const float* __restrict__ edge_attr,
                           float* deg, float* ea_sum) {
    int e = blockIdx.x * blockDim.x + threadIdx.x;
    if (e >= E_EDGES) return;
    int d = ei[E_EDGES + e];
    atomicAdd(&deg[d], 1.0f);
    atomicAdd(&ea_sum[2 * d + 0], edge_attr[2 * e + 0]);
    atomicAdd(&ea_sum[2 * d + 1], edge_attr[2 * e + 1]);
}

__global__ __launch_bounds__(1024) void scan_kernel(const float* __restrict__ deg, int* row_ptr) {
    __shared__ int part[1024];
    int t = threadIdx.x;
    int base = t * 32;
    int loc[32];
    int s = 0;
    #pragma unroll
    for (int j = 0; j < 32; j++) {
        loc[j] = s;
        s += (int)deg[base + j] + 1;
    }
    int mysum = s;
    part[t] = s;
    __syncthreads();
    for (int off = 1; off < 1024; off <<= 1) {
        int v = 0;
        if (t >= off) v = part[t - off];
        __syncthreads();
        part[t] += v;
        __syncthreads();
    }
    int offset = part[t] - mysum;
    #pragma unroll
    for (int j = 0; j < 32; j++) row_ptr[base + j] = offset + loc[j];
    if (t == 1023) row_ptr[N_NODES] = part[1023];
}

// CSR fill with PACKED 16B edge records: {src, ea0, ea1, 0}; self-loop mean inline
__global__ void fill_kernel(const int* __restrict__ ei, const float* __restrict__ edge_attr,
                            const float* __restrict__ ea_sum, const float* __restrict__ deg,
                            const int* __restrict__ row_ptr, int* fill, int4* __restrict__ erec) {
    int tid = blockIdx.x * blockDim.x + threadIdx.x;
    if (tid >= E_EDGES + N_NODES) return;
    int d, src; float a0, a1;
    if (tid < E_EDGES) {
        d = ei[E_EDGES + tid];
        src = ei[tid];
        a0 = edge_attr[2 * tid + 0];
        a1 = edge_attr[2 * tid + 1];
    } else {
        d = tid - E_EDGES;
        src = d;
        float dm = fmaxf(deg[d], 1.0f);
        a0 = ea_sum[2 * d + 0] / dm;
        a1 = ea_sum[2 * d + 1] / dm;
    }
    int pos = row_ptr[d] + atomicAdd(&fill[d], 1);
    int4 r;
    r.x = src;
    r.y = __float_as_int(a0);
    r.z = __float_as_int(a1);
    r.w = 0;
    erec[pos] = r;
}

// ---------------- all conversions in one launch ----------------
// wcat rows: 0..767 in_proj (q rows prescaled by SCALE*log2e), 768..1023 W_l^T, 1024..1279 W_r^T
#define QSCALE 0.25506882685716462f
__global__ void convall(const float* __restrict__ x,
                        const float* __restrict__ W_l, const float* __restrict__ W_r,
                        const float* __restrict__ W1, const float* __restrict__ W2,
                        const float* __restrict__ in_proj_w, const float* __restrict__ out_proj_w,
                        const float* __restrict__ b_l, const float* __restrict__ b_r,
                        const float* __restrict__ in_proj_b,
                        bf16* xb, bf16* wcat, bf16* w1b, bf16* w2b,
                        bf16* wopb, float* bcat)
{
    int b = blockIdx.x, t = threadIdx.x;
    if (b < 8192) {                      // x copy (float4)
        int i = b * 256 + t;
        store4(&xb[i * 4], *(const float4*)&x[i * 4]);
    } else if (b < 8960) {               // in_proj_w [768][256] copy; q rows scaled
        int i = (b - 8192) * 256 + t;
        float v = in_proj_w[i];
        if (i < 65536) v *= QSCALE;
        wcat[i] = f2bf(v);
    } else if (b < 9216) {               // W_l^T -> wcat rows 768..1023
        int i = (b - 8960) * 256 + t; int k = i >> 8, n = i & 255;
        wcat[(768 + n) * 256 + k] = f2bf(W_l[i]);
    } else if (b < 9472) {               // W_r^T -> wcat rows 1024..1279
        int i = (b - 9216) * 256 + t; int k = i >> 8, n = i & 255;
        wcat[(1024 + n) * 256 + k] = f2bf(W_r[i]);
    } else if (b < 10496) {              // W1 [256][1024] -> w1b[n*256+k]
        int i = (b - 9472) * 256 + t; int k = i >> 10, n = i & 1023;
        w1b[n * 256 + k] = f2bf(W1[i]);
    } else if (b < 11520) {              // W2 [1024][256] -> w2b[n*1024+k]
        int i = (b - 10496) * 256 + t; int k = i >> 8, n = i & 255;
        w2b[n * 1024 + k] = f2bf(W2[i]);
    } else if (b < 11584) {              // out_proj_w straight
        int i = (b - 11520) * 256 + t;
        store4(&wopb[i * 4], *(const float4*)&out_proj_w[i * 4]);
    } else {                             // bcat: scaled in_proj_b | b_l | b_r
        #pragma unroll
        for (int j = 0; j < 5; j++) {
            int idx = j * 256 + t;
            float v;
            if (idx < 768) { v = in_proj_b[idx]; if (idx < 256) v *= QSCALE; }
            else if (idx < 1024) v = b_l[idx - 768];
            else v = b_r[idx - 1024];
            bcat[idx] = v;
        }
    }
}

// ---------------- MFMA bf16 GEMM (m97-style staging + XCD-locality swizzle) --
// EPI: 0 bias, 1 bias+gelu, 4 bias+residual(res bf16)->fp32 (float*)C,
//      5 merged 5-slab routing: slabs 0-2 -> qkv[gm*768+gn], 3 -> res(xl), 4 -> d2(xr)
template <int EPI>
__global__ __launch_bounds__(256) void mfma_gemm(
    const bf16* __restrict__ A, const bf16* __restrict__ Wb,
    const float* __restrict__ bias, const bf16* __restrict__ res,
    bf16* __restrict__ C, int M, int N, int K, bf16* __restrict__ d2)
{
    __shared__ bf16 lds[2 * 128 * 64];
    bf16* As = lds;
    bf16* Bs = lds + 128 * 64;
    int tid = threadIdx.x;
    int wave = tid >> 6, lane = tid & 63;
    int quad = lane >> 4, l16 = lane & 15;
    // XCD-bijective swizzle: blocks sharing an A-tile (same by) land on ONE XCD
    int nbx = gridDim.x;
    int lid = blockIdx.y * nbx + blockIdx.x;
    int chunk = (nbx * gridDim.y) >> 3;
    int nlid = (lid & 7) * chunk + (lid >> 3);
    int bx = nlid % nbx;
    int by = nlid / nbx;
    int n0 = bx * 128, m0 = by * 128;
    int wm = (wave & 1) * 64, wn = (wave >> 1) * 64;

    f4 acc[4][4] = {};
    int srow = tid >> 3;
    int scol = (tid & 7) * 8;

    for (int k0 = 0; k0 < K; k0 += 64) {
        #pragma unroll
        for (int i = 0; i < 4; i++) {
            int row = i * 32 + srow;
            cp16(&A[(size_t)(m0 + row) * K + k0 + scol], &As[row * 64 + scol]);
            cp16(&Wb[(size_t)(n0 + row) * K + k0 + scol], &Bs[row * 64 + scol]);
        }
        __syncthreads();
        #pragma unroll
        for (int ks = 0; ks < 2; ks++) {
            short8 af[4], bfr[4];
            #pragma unroll
            for (int mt = 0; mt < 4; mt++)
                af[mt] = *(const short8*)&As[(wm + mt * 16 + l16) * 64 + ks * 32 + quad * 8];
            #pragma unroll
            for (int nt = 0; nt < 4; nt++)
                bfr[nt] = *(const short8*)&Bs[(wn + nt * 16 + l16) * 64 + ks * 32 + quad * 8];
            #pragma unroll
            for (int mt = 0; mt < 4; mt++)
                #pragma unroll
                for (int nt = 0; nt < 4; nt++)
                    acc[mt][nt] = __builtin_amdgcn_mfma_f32_16x16x32_bf16(
                        af[mt], bfr[nt], acc[mt][nt], 0, 0, 0);
        }
        __syncthreads();
    }

    float* epi = (float*)lds + wave * 16 * 68;
    int row = lane >> 2;
    int cb = (lane & 3) * 16;
    int gn = n0 + wn + cb;
    float bb[16];
    *(float4*)&bb[0]  = *(const float4*)&bias[gn + 0];
    *(float4*)&bb[4]  = *(const float4*)&bias[gn + 4];
    *(float4*)&bb[8]  = *(const float4*)&bias[gn + 8];
    *(float4*)&bb[12] = *(const float4*)&bias[gn + 12];

    for (int mt = 0; mt < 4; mt++) {
        #pragma unroll
        for (int nt = 0; nt < 4; nt++)
            #pragma unroll
            for (int r = 0; r < 4; r++)
                epi[(quad * 4 + r) * 68 + nt * 16 + l16] = acc[mt][nt][r];
        float vv[16];
        *(float4*)&vv[0]  = *(float4*)&epi[row * 68 + cb + 0];
        *(float4*)&vv[4]  = *(float4*)&epi[row * 68 + cb + 4];
        *(float4*)&vv[8]  = *(float4*)&epi[row * 68 + cb + 8];
        *(float4*)&vv[12] = *(float4*)&epi[row * 68 + cb + 12];
        int gm = m0 + wm + mt * 16 + row;
        #pragma unroll
        for (int j = 0; j < 16; j++) vv[j] += bb[j];
        if (EPI == 1) {
            #pragma unroll
            for (int j = 0; j < 16; j++)
                vv[j] = gelu_fast(vv[j]);
        } else if (EPI == 4) {
            ushort rr[16];
            const bf16* rp = &res[(size_t)gm * N + gn];
            *(int4*)&rr[0] = *(const int4*)&rp[0];
            *(int4*)&rr[8] = *(const int4*)&rp[8];
            #pragma unroll
            for (int j = 0; j < 16; j++) vv[j] += bf2f(rr[j]);
            float* cf = (float*)C + (size_t)gm * N + gn;
            *(float4*)&cf[0]  = *(float4*)&vv[0];
            *(float4*)&cf[4]  = *(float4*)&vv[4];
            *(float4*)&cf[8]  = *(float4*)&vv[8];
            *(float4*)&cf[12] = *(float4*)&vv[12];
            continue;
        }
        ushort o16[16];
        #pragma unroll
        for (int j = 0; j < 16; j++) o16[j] = f2bf(vv[j]);
        bf16* cp;
        if (EPI == 5) {
            if (gn < 768) {
                cp = &C[(size_t)gm * 768 + gn];           // interleaved qkv
            } else if (gn < 1024) {
                cp = &((bf16*)res)[(size_t)gm * 256 + (gn - 768)];   // xl
            } else {
                cp = &d2[(size_t)gm * 256 + (gn - 1024)];            // xr
            }
        } else {
            cp = &C[(size_t)gm * N + gn];
        }
        *(int4*)&cp[0] = *(int4*)&o16[0];
        *(int4*)&cp[8] = *(int4*)&o16[8];
    }
}

// ---------------- fused FFN v3: weights global->VGPR, minimal LDS ----------
// 64-row slab/block, 16 chunks of 64 h1-cols.  W1/W2 fragments are loaded
// DIRECTLY global->register (each lane's frag is a contiguous 16B run; a
// wave's frag = 16 full 64B lines; weights are L2-resident, reused by all
// 512 blocks).  LDS = Asl 32K (combined, swz512) + H1 9K ([64][72] bf16,
// 144B stride -> conflict-free b128) + stats 2K = 44K -> >=2 blocks/CU.
// 2 barriers per chunk (H1 WAR/RAW only).  LN3 via per-row stats reduction
// (shuffle over 16-lane groups + 2KB LDS cross-wave), no 64KB fp32 buffer.
__global__ __launch_bounds__(256) void ffn_fused(
    const bf16* __restrict__ combined,
    const bf16* __restrict__ w1b, const bf16* __restrict__ w2b,
    const float* __restrict__ b1, const float* __restrict__ b2,
    const float* __restrict__ g3, const float* __restrict__ be3,
    float* __restrict__ out)
{
    __shared__ __attribute__((aligned(16))) char smem[44032];
    char* Asl_c = smem;                        // 32 KB combined slab (swz512)
    char* H1_c  = smem + 32768;                // 9216 B: [64 rows][72 cols] bf16
    float* stats = (float*)(smem + 41984);     // [64 rows][4 waves][2] = 2 KB

    int tid = threadIdx.x;
    int wave = tid >> 6, lane = tid & 63;
    int quad = lane >> 4, l16 = lane & 15;
    int m0 = blockIdx.x * 64;
    int wn1 = wave * 16;               // gemm1 n-strip within 64-col chunk
    int wn2 = wave * 64;               // gemm2 out-col strip

    // stage combined slab: linear dest o, source from logical L = o^swz
    #pragma unroll
    for (int rr = 0; rr < 8; rr++) {
        int o = rr * 4096 + tid * 16;
        int L = o ^ (((o >> 9) & 7) << 4);
        int row = L >> 9, colb = L & 511;
        cp16((const bf16*)((const char*)combined + (size_t)(m0 + row) * 512 + colb),
             (bf16*)(Asl_c + o));
    }

    // per-lane weight fragment base pointers (contiguous 16B runs)
    const bf16* wp2b[4];
    #pragma unroll
    for (int nt = 0; nt < 4; nt++)
        wp2b[nt] = w2b + (size_t)(wn2 + nt * 16 + l16) * 1024 + quad * 8;

    f4 oacc[4][4] = {};
    __syncthreads();                           // Asl staged (vmcnt drained)

    for (int j = 0; j < 16; j++) {
        // W1 frags for this chunk: rows j*64+wn1+l16, 8 k-slices (used first)
        short8 wf1[8];
        const bf16* wp1 = w1b + (size_t)(j * 64 + wn1 + l16) * 256 + quad * 8;
        #pragma unroll
        for (int ks = 0; ks < 8; ks++) wf1[ks] = *(const short8*)(wp1 + ks * 32);
        // W2 frags (used after the H1 phase -> latency fully hidden)
        short8 wf2[8];
        #pragma unroll
        for (int nt = 0; nt < 4; nt++)
            #pragma unroll
            for (int ks = 0; ks < 2; ks++)
                wf2[nt * 2 + ks] = *(const short8*)(wp2b[nt] + j * 64 + ks * 32);

        // gemm1: 64x16 strip over K=256  (overlaps other waves' barrier wait)
        f4 acc1[4] = {};
        #pragma unroll
        for (int ks = 0; ks < 8; ks++) {
            short8 af[4];
            #pragma unroll
            for (int mt = 0; mt < 4; mt++) {
                int r_ = mt * 16 + l16;
                af[mt] = *(const short8*)(Asl_c +
                    ((r_ * 512 + ks * 64 + quad * 16) ^ ((r_ & 7) << 4)));
            }
            #pragma unroll
            for (int mt = 0; mt < 4; mt++)
                acc1[mt] = __builtin_amdgcn_mfma_f32_16x16x32_bf16(
                    af[mt], wf1[ks], acc1[mt], 0, 0, 0);
        }
        float b1v = b1[j * 64 + wn1 + l16];
        __syncthreads();                       // prev chunk's H1 reads all done
        // gelu -> H1 chunk
        #pragma unroll
        for (int mt = 0; mt < 4; mt++)
            #pragma unroll
            for (int r = 0; r < 4; r++) {
                float v = gelu_fast(acc1[mt][r] + b1v);
                int row = mt * 16 + quad * 4 + r;
                *(bf16*)(H1_c + row * 144 + (wn1 + l16) * 2) = f2bf(v);
            }
        __syncthreads();                       // H1 visible to all waves
        // gemm2 partial: oacc += h1chunk @ W2chunk (K'=64)
        #pragma unroll
        for (int ks = 0; ks < 2; ks++) {
            short8 af2[4];
            #pragma unroll
            for (int mt = 0; mt < 4; mt++)
                af2[mt] = *(const short8*)(H1_c +
                    (mt * 16 + l16) * 144 + ks * 64 + quad * 16);
            #pragma unroll
            for (int mt = 0; mt < 4; mt++)
                #pragma unroll
                for (int nt = 0; nt < 4; nt++)
                    oacc[mt][nt] = __builtin_amdgcn_mfma_f32_16x16x32_bf16(
                        af2[mt], wf2[nt * 2 + ks], oacc[mt][nt], 0, 0, 0);
        }
    }

    // epilogue: bias + residual(from Asl, swizzled) folded into regs
    #pragma unroll
    for (int nt = 0; nt < 4; nt++) {
        float b2v = b2[wn2 + nt * 16 + l16];
        #pragma unroll
        for (int mt = 0; mt < 4; mt++)
            #pragma unroll
            for (int r = 0; r < 4; r++) {
                int rl = mt * 16 + quad * 4 + r;
                int gn = wn2 + nt * 16 + l16;
                int o = (rl * 512 + gn * 2) ^ ((rl & 7) << 4);
                oacc[mt][nt][r] += b2v + bf2f(*(const bf16*)(Asl_c + o));
            }
    }

    // LN3 row stats: per-lane partials over its 4 cols/row, 16-lane shuffle
    // reduce (lanes of one quad hold the same rows), cross-wave via 2KB LDS.
    #pragma unroll
    for (int mt = 0; mt < 4; mt++)
        #pragma unroll
        for (int r = 0; r < 4; r++) {
            float s = 0.f, q = 0.f;
            #pragma unroll
            for (int nt = 0; nt < 4; nt++) {
                float v = oacc[mt][nt][r];
                s += v; q += v * v;
            }
            s += __shfl_xor(s, 1); q += __shfl_xor(q, 1);
            s += __shfl_xor(s, 2); q += __shfl_xor(q, 2);
            s += __shfl_xor(s, 4); q += __shfl_xor(q, 4);
            s += __shfl_xor(s, 8); q += __shfl_xor(q, 8);
            if (l16 == 0) {
                int row = mt * 16 + quad * 4 + r;
                stats[row * 8 + wave * 2 + 0] = s;
                stats[row * 8 + wave * 2 + 1] = q;
            }
        }
    __syncthreads();

    float g3v[4], be3v[4];
    #pragma unroll
    for (int nt = 0; nt < 4; nt++) {
        g3v[nt]  = g3[wn2 + nt * 16 + l16];
        be3v[nt] = be3[wn2 + nt * 16 + l16];
    }
    #pragma unroll
    for (int mt = 0; mt < 4; mt++)
        #pragma unroll
        for (int r = 0; r < 4; r++) {
            int row = mt * 16 + quad * 4 + r;
            float s = stats[row * 8 + 0] + stats[row * 8 + 2]
                    + stats[row * 8 + 4] + stats[row * 8 + 6];
            float q = stats[row * 8 + 1] + stats[row * 8 + 3]
                    + stats[row * 8 + 5] + stats[row * 8 + 7];
            float mean = s * (1.0f / 256.0f);
            float var = fmaxf(q * (1.0f / 256.0f) - mean * mean, 0.0f);
            float rstd = rsqrtf(var + 1e-5f);
            #pragma unroll
            for (int nt = 0; nt < 4; nt++) {
                float v = (oacc[mt][nt][r] - mean) * rstd * g3v[nt] + be3v[nt];
                out[(size_t)(m0 + row) * 256 + wn2 + nt * 16 + l16] = v;
            }
        }
}

// ---------------- MFMA flash attention (q prescaled; exp2; trunc pack) ----
__global__ __launch_bounds__(256) void attn_mfma(
    const bf16* __restrict__ qkv, bf16* __restrict__ attnout)
{
    __shared__ bf16 Ks[128 * 40];
    __shared__ bf16 Vt[32 * 136];
    __shared__ bf16 Pb[4 * 64 * 40];

    int b = blockIdx.x;
    int g = b >> 4, h = (b >> 1) & 7, hlf = b & 1;
    int tid = threadIdx.x;
    int wave = tid >> 6, lane = tid & 63;
    int quad = lane >> 4, l16 = lane & 15;
    int qbase = hlf * 256 + wave * 64;
    bf16* Pw = &Pb[wave * 64 * 40];

    short8 qf[4];
    #pragma unroll
    for (int mt = 0; mt < 4; mt++) {
        size_t node = (size_t)(g * NPG + qbase + mt * 16 + l16);
        qf[mt] = *(const short8*)&qkv[node * 768 + h * CDIM + quad * 8];
    }

    f4 oacc[4][2] = {};
    float lacc[4][4] = {};

    for (int c = 0; c < 4; c++) {
        int kk0 = c * 128;
        __syncthreads();
        #pragma unroll
        for (int i = 0; i < 2; i++) {
            int idx = i * 256 + tid;
            int key = idx >> 2, kc = (idx & 3) * 8;
            *(int4*)&Ks[key * 40 + kc] =
                *(const int4*)&qkv[(size_t)(g * NPG + kk0 + key) * 768 + 256 + h * CDIM + kc];
        }
        {
            int key = tid >> 1, dblk = (tid & 1) * 16;
            ushort tmp[16];
            const bf16* vp = &qkv[(size_t)(g * NPG + kk0 + key) * 768 + 512 + h * CDIM + dblk];
            *(int4*)&tmp[0] = *(const int4*)&vp[0];
            *(int4*)&tmp[8] = *(const int4*)&vp[8];
            #pragma unroll
            for (int j = 0; j < 16; j++) Vt[(dblk + j) * 136 + key] = tmp[j];
        }
        __syncthreads();

        for (int sub = 0; sub < 4; sub++) {
            int ks0 = sub * 32;
            short8 kf[2];
            #pragma unroll
            for (int nt = 0; nt < 2; nt++)
                kf[nt] = *(const short8*)&Ks[(ks0 + nt * 16 + l16) * 40 + quad * 8];
            #pragma unroll
            for (int mt = 0; mt < 4; mt++) {
                #pragma unroll
                for (int nt = 0; nt < 2; nt++) {
                    f4 z = {0.f, 0.f, 0.f, 0.f};
                    f4 s = __builtin_amdgcn_mfma_f32_16x16x32_bf16(qf[mt], kf[nt], z, 0, 0, 0);
                    #pragma unroll
                    for (int r = 0; r < 4; r++) {
                        float p = exp2f(s[r]);
                        lacc[mt][r] += p;
                        Pw[(mt * 16 + quad * 4 + r) * 40 + nt * 16 + l16] = f2bf_trunc(p);
                    }
                }
            }
            short8 vf[2];
            #pragma unroll
            for (int dt = 0; dt < 2; dt++)
                vf[dt] = *(const short8*)&Vt[(dt * 16 + l16) * 136 + ks0 + quad * 8];
            #pragma unroll
            for (int mt = 0; mt < 4; mt++) {
                short8 pf = *(const short8*)&Pw[(mt * 16 + l16) * 40 + quad * 8];
                #pragma unroll
                for (int dt = 0; dt < 2; dt++)
                    oacc[mt][dt] = __builtin_amdgcn_mfma_f32_16x16x32_bf16(
                        pf, vf[dt], oacc[mt][dt], 0, 0, 0);
            }
        }
    }

    #pragma unroll
    for (int mt = 0; mt < 4; mt++)
        #pragma unroll
        for (int r = 0; r < 4; r++) {
            float l = lacc[mt][r];
            l += __shfl_xor(l, 1);
            l += __shfl_xor(l, 2);
            l += __shfl_xor(l, 4);
            l += __shfl_xor(l, 8);
            lacc[mt][r] = l;
        }

    #pragma unroll
    for (int mt = 0; mt < 4; mt++) {
        #pragma unroll
        for (int dt = 0; dt < 2; dt++) {
            #pragma unroll
            for (int r = 0; r < 4; r++) {
                float v = oacc[mt][dt][r] / lacc[mt][r];
                size_t node = (size_t)(g * NPG + qbase + mt * 16 + quad * 4 + r);
                attnout[node * HIDDEN + h * CDIM + dt * 16 + l16] = f2bf(v);
            }
        }
    }
}

// ---------------- GATv2: 2 waves/node + depth-2 pipeline (r8-proven) ----
__device__ __forceinline__ void fetchrec(
    int i, int re, int node, const int4* __restrict__ erec,
    int& s, float& a0, float& a1)
{
    if (i < re) {
        int4 r = erec[i];
        s = r.x; a0 = __int_as_float(r.y); a1 = __int_as_float(r.z);
    } else {
        s = node; a0 = 0.f; a1 = 0.f;
    }
}

__global__ __launch_bounds__(256) void gat_kernel(
    const bf16* __restrict__ xl, const bf16* __restrict__ xr,
    const int* __restrict__ row_ptr, const int4* __restrict__ erec,
    const float* __restrict__ W_e, const float* __restrict__ att,
    const float* __restrict__ bias_gat,
    const float* __restrict__ g1, const float* __restrict__ be1,
    bf16* __restrict__ out)
{
    __shared__ float pacc[2][260];
    __shared__ float plsum[2][64];
    int wave = threadIdx.x >> 6;
    int lane = threadIdx.x & 63;
    int nloc = wave >> 1, half = wave & 1;
    int node = blockIdx.x * 2 + nloc;
    int cb = lane * 4;

    float4 xr4 = load4(&xr[(size_t)node * 256 + cb]);
    float4 we0 = *(const float4*)&W_e[cb];
    float4 we1 = *(const float4*)&W_e[HIDDEN + cb];
    float4 at4 = *(const float4*)&att[cb];

    int rs = row_ptr[node], re = row_ptr[node + 1];

    float lsum = 0.f;
    float acc0 = 0.f, acc1 = 0.f, acc2 = 0.f, acc3 = 0.f;

    int i0 = rs + half;
    int s0, s1; float a00, a01, a10, a11;
    fetchrec(i0,     re, node, erec, s0, a00, a01);
    fetchrec(i0 + 2, re, node, erec, s1, a10, a11);
    ushort4 xu0 = *(const ushort4*)&xl[(size_t)s0 * 256 + cb];

    for (int i = i0; i < re; i += 2) {
        int s2; float a20, a21;
        fetchrec(i + 4, re, node, erec, s2, a20, a21);
        ushort4 xu1 = *(const ushort4*)&xl[(size_t)s1 * 256 + cb];

        float4 xl4 = make_float4(bf2f(xu0.x), bf2f(xu0.y), bf2f(xu0.z), bf2f(xu0.w));
        float t, p = 0.f;
        t = xl4.x + xr4.x + a00 * we0.x + a01 * we1.x; t = (t > 0.f) ? t : 0.2f * t; p += t * at4.x;
        t = xl4.y + xr4.y + a00 * we0.y + a01 * we1.y; t = (t > 0.f) ? t : 0.2f * t; p += t * at4.y;
        t = xl4.z + xr4.z + a00 * we0.z + a01 * we1.z; t = (t > 0.f) ? t : 0.2f * t; p += t * at4.z;
        t = xl4.w + xr4.w + a00 * we0.w + a01 * we1.w; t = (t > 0.f) ? t : 0.2f * t; p += t * at4.w;
        p += __shfl_xor(p, 1);
        p += __shfl_xor(p, 2);
        p += __shfl_xor(p, 4);
        float w = __expf(p);
        lsum += w;
        acc0 += w * xl4.x; acc1 += w * xl4.y; acc2 += w * xl4.z; acc3 += w * xl4.w;

        s0 = s1; a00 = a10; a01 = a11; xu0 = xu1;
        s1 = s2; a10 = a20; a11 = a21;
    }

    if (half) {
        plsum[nloc][lane] = lsum;
        pacc[nloc][cb + 0] = acc0; pacc[nloc][cb + 1] = acc1;
        pacc[nloc][cb + 2] = acc2; pacc[nloc][cb + 3] = acc3;
    }
    __syncthreads();
    if (!half) {
        lsum += plsum[nloc][lane];
        acc0 += pacc[nloc][cb + 0]; acc1 += pacc[nloc][cb + 1];
        acc2 += pacc[nloc][cb + 2]; acc3 += pacc[nloc][cb + 3];

        float inv = 1.0f / lsum;
        float v0 = acc0 * inv + bias_gat[cb + 0];
        float v1 = acc1 * inv + bias_gat[cb + 1];
        float v2 = acc2 * inv + bias_gat[cb + 2];
        float v3 = acc3 * inv + bias_gat[cb + 3];

        float s = v0 + v1 + v2 + v3;
        #pragma unroll
        for (int m = 1; m < 64; m <<= 1) s += __shfl_xor(s, m);
        float mean = s * (1.0f / 256.0f);
        float d0 = v0 - mean, d1 = v1 - mean, d2 = v2 - mean, d3 = v3 - mean;
        float sq = d0 * d0 + d1 * d1 + d2 * d2 + d3 * d3;
        #pragma unroll
        for (int m = 1; m < 64; m <<= 1) sq += __shfl_xor(sq, m);
        float rstd = rsqrtf(sq * (1.0f / 256.0f) + 1e-5f);
        float4 o;
        o.x = d0 * rstd * g1[cb + 0] + be1[cb + 0];
        o.y = d1 * rstd * g1[cb + 1] + be1[cb + 1];
        o.z = d2 * rstd * g1[cb + 2] + be1[cb + 2];
        o.w = d3 * rstd * g1[cb + 3] + be1[cb + 3];
        store4(&out[(size_t)node * HIDDEN + cb], o);
    }
}

// ---------------- LN2(gout) + gated combine ----------------
__global__ __launch_bounds__(256) void combine_kernel(
    const bf16* __restrict__ gout, const bf16* __restrict__ localout,
    const float* __restrict__ alpha_p,
    const float* __restrict__ g2, const float* __restrict__ be2,
    bf16* __restrict__ combined)
{
    int wave = threadIdx.x >> 6;
    int lane = threadIdx.x & 63;
    int node = blockIdx.x * 4 + wave;
    int cb = lane * 4;
    float4 gv = load4(&gout[(size_t)node * HIDDEN + cb]);
    float s = gv.x + gv.y + gv.z + gv.w;
    #pragma unroll
    for (int m = 1; m < 64; m <<= 1) s += __shfl_xor(s, m);
    float mean = s * (1.0f / 256.0f);
    float d0 = gv.x - mean, d1 = gv.y - mean, d2 = gv.z - mean, d3 = gv.w - mean;
    float sq = d0 * d0 + d1 * d1 + d2 * d2 + d3 * d3;
    #pragma unroll
    for (int m = 1; m < 64; m <<= 1) sq += __shfl_xor(sq, m);
    float rstd = rsqrtf(sq * (1.0f / 256.0f) + 1e-5f);
    float n0 = d0 * rstd * g2[cb + 0] + be2[cb + 0];
    float n1 = d1 * rstd * g2[cb + 1] + be2[cb + 1];
    float n2 = d2 * rstd * g2[cb + 2] + be2[cb + 2];
    float n3 = d3 * rstd * g2[cb + 3] + be2[cb + 3];
    float a = 1.0f / (1.0f + __expf(-alpha_p[0]));
    float4 lv = load4(&localout[(size_t)node * HIDDEN + cb]);
    float4 o;
    o.x = a * lv.x + (1.0f - a) * n0;
    o.y = a * lv.y + (1.0f - a) * n1;
    o.z = a * lv.z + (1.0f - a) * n2;
    o.w = a * lv.w + (1.0f - a) * n3;
    store4(&combined[(size_t)node * HIDDEN + cb], o);
}

// ---------------- launch ----------------
extern "C" void kernel_launch(void* const* d_in, const int* in_sizes, int n_in,
                              void* d_out, int out_size, void* d_ws, size_t ws_size,
                              hipStream_t stream) {
    const float* x          = (const float*)d_in[0];
    const float* edge_attr  = (const float*)d_in[1];
    const float* W_l        = (const float*)d_in[2];
    const float* b_l        = (const float*)d_in[3];
    const float* W_r        = (const float*)d_in[4];
    const float* b_r        = (const float*)d_in[5];
    const float* W_e        = (const float*)d_in[6];
    const float* att        = (const float*)d_in[7];
    const float* bias_gat   = (const float*)d_in[8];
    const float* in_proj_w  = (const float*)d_in[9];
    const float* in_proj_b  = (const float*)d_in[10];
    const float* out_proj_w = (const float*)d_in[11];
    const float* out_proj_b = (const float*)d_in[12];
    const float* alpha_p    = (const float*)d_in[13];
    const float* W1         = (const float*)d_in[14];
    const float* b1         = (const float*)d_in[15];
    const float* W2         = (const float*)d_in[16];
    const float* b2         = (const float*)d_in[17];
    const float* g1  = (const float*)d_in[18];
    const float* be1 = (const float*)d_in[19];
    const float* g2  = (const float*)d_in[20];
    const float* be2 = (const float*)d_in[21];
    const float* g3  = (const float*)d_in[22];
    const float* be3 = (const float*)d_in[23];
    const int* edge_index = (const int*)d_in[24];

    char* base = (char*)d_ws;
    const size_t MB = 1024 * 1024;
    const size_t KB = 1024;
    // graph prep [0, 3 MiB)
    float* deg     = (float*)(base + 0);
    float* ea_sum  = (float*)(base + 131072);
    int*   fill    = (int*)  (base + 393216);
    int*   row_ptr = (int*)  (base + 524288);
    // bf16 weights [3 MiB, ~5 MiB)
    bf16* wcat = (bf16*)(base + 3 * MB);              // 1280x256 (640 KB)
    bf16* w1b  = (bf16*)(base + 3 * MB + 704 * KB);   // 1024x256 (512 KB)
    bf16* w2b  = (bf16*)(base + 3 * MB + 1216 * KB);  // 256x1024 (512 KB)
    bf16* wopb = (bf16*)(base + 3 * MB + 1728 * KB);  // 256x256  (128 KB)
    float* bcat = (float*)(base + 5 * MB);            // 1280 floats
    // big bf16 buffers (aliased)
    bf16* xb       = (bf16*)(base + 8 * MB);    // [8,24)
    bf16* qkv      = (bf16*)(base + 24 * MB);   // [24,72)  alive: merged GEMM .. attn
    bf16* attnout  = (bf16*)(base + 8 * MB);    // [8,24)   (xb dead after merged GEMM)
    bf16* gout     = (bf16*)(base + 24 * MB);   // [24,40)  (qkv dead after attn)
    bf16* localout = (bf16*)(base + 40 * MB);   // [40,56)
    bf16* combined = (bf16*)(base + 56 * MB);   // [56,72)
    int4* erec     = (int4*)(base + 88 * MB);   // [88, 96.6)
    bf16* xl_      = (bf16*)(base + 72 * MB);   // [72,88)
    bf16* xr_      = (bf16*)(base + 104 * MB);  // [104,120)
    float* out = (float*)d_out;

    // ---- GAT graph prep ----
    zero_kernel<<<(2 * N_NODES + 255) / 256, 256, 0, stream>>>(deg, ea_sum, fill);
    deg_kernel<<<E_EDGES / 256, 256, 0, stream>>>(edge_index, edge_attr, deg, ea_sum);
    scan_kernel<<<1, 1024, 0, stream>>>(deg, row_ptr);
    fill_kernel<<<(E_EDGES + N_NODES + 255) / 256, 256, 0, stream>>>(
        edge_index, edge_attr, ea_sum, deg, row_ptr, fill, erec);

    // ---- conversions (single launch) ----
    convall<<<11585, 256, 0, stream>>>(x, W_l, W_r, W1, W2, in_proj_w, out_proj_w,
                                       b_l, b_r, in_proj_b,
                                       xb, wcat, w1b, w2b, wopb, bcat);

    // ---- merged qkv|xl|xr GEMM (one pass over xb) ----
    mfma_gemm<5><<<dim3(10, 256), 256, 0, stream>>>(
        xb, wcat, bcat, xl_, qkv, N_NODES, 1280, 256, xr_);

    // ---- attention, then gat (qkv frees buffers for downstream) ----
    attn_mfma<<<NGRAPH * NHEAD * 2, 256, 0, stream>>>(qkv, attnout);
    gat_kernel<<<N_NODES / 2, 256, 0, stream>>>(
        xl_, xr_, row_ptr, erec, W_e, att, bias_gat, g1, be1, localout);

    // ---- out_proj ----
    mfma_gemm<0><<<dim3(2, 256), 256, 0, stream>>>(
        attnout, wopb, out_proj_b, (const bf16*)nullptr, gout, N_NODES, 256, 256, (bf16*)nullptr);

    // ---- LN2 + gated combine ----
    combine_kernel<<<N_NODES / 4, 256, 0, stream>>>(
        gout, localout, alpha_p, g2, be2, combined);

    // ---- fused FFN1+gelu+FFN2+residual+LN3 -> fp32 out ----
    ffn_fused<<<N_NODES / 64, 256, 0, stream>>>(
        combined, w1b, w2b, b1, b2, g3, be3, out);
}